// Round 1
// baseline (1280.649 us; speedup 1.0000x reference)
//
#include <hip/hip_runtime.h>

#define NTRAIN 1024
#define NY 2
#define DDIM 128
#define NB 256
#define NITER 16
#define TT 1026          // NTRAIN + NY
#define TP 1088          // padded to 64-multiple
#define SCALE_C 0.25f
#define GAMMA_C 0.05f
#define TAU_C 256.0f     // 2*D

__device__ __forceinline__ float sigm(float x) {
    return 1.0f / (1.0f + __expf(-x));
}

// ---------------- prep: p, base_logit, xsq, labels ----------------
__global__ void k_prep(const float* __restrict__ Xtr, const float* __restrict__ Xdef,
                       const float* __restrict__ worder, const float* __restrict__ wbase,
                       const int* __restrict__ ytr,
                       float* __restrict__ p, float* __restrict__ bl,
                       float* __restrict__ xsq, int* __restrict__ lbl) {
    int t = blockIdx.x;        // 0..TP-1
    int tx = threadIdx.x;      // 128 threads
    __shared__ float sp[128], sb[128], ss[128];
    float po = 0.f, bo = 0.f, sq = 0.f;
    if (t < TT) {
        const float* row = (t < NTRAIN) ? (Xtr + (size_t)t * DDIM)
                                        : (Xdef + (size_t)(t - NTRAIN) * DDIM);
        float x = row[tx];
        po = x * worder[tx];
        bo = x * wbase[tx];
        sq = x * x;
    }
    sp[tx] = po; sb[tx] = bo; ss[tx] = sq;
    __syncthreads();
    for (int off = 64; off > 0; off >>= 1) {
        if (tx < off) { sp[tx] += sp[tx+off]; sb[tx] += sb[tx+off]; ss[tx] += ss[tx+off]; }
        __syncthreads();
    }
    if (tx == 0) {
        p[t] = sp[0]; bl[t] = sb[0]; xsq[t] = ss[0];
        lbl[t] = (t < NTRAIN) ? ytr[t] : ((t < TT) ? (t - NTRAIN) : -1);
    }
}

// ---------------- Es[i,j] (default rows + pad zeroed) ----------------
__global__ void k_es(const float* __restrict__ p, float* __restrict__ Es) {
    int j = blockIdx.x * blockDim.x + threadIdx.x;
    int i = blockIdx.y;
    if (j >= TP) return;
    float v = 0.f;
    if (i < NTRAIN && j < TT) {   // is_default rows (i>=NTRAIN) and pads -> 0
        float x = SCALE_C * (p[i] - p[j]);
        float a = sigm(x);
        float b = sigm(-x);
        v = a * (1.f - b);
    }
    Es[(size_t)i * TP + j] = v;
}

// ---------------- blocked product + assemble A ----------------
#define BT 64
#define KC 32
__global__ __launch_bounds__(256) void k_ablk(const float* __restrict__ Es,
                                              const float* __restrict__ p,
                                              const int* __restrict__ lbl,
                                              float* __restrict__ Amat) {
    __shared__ float Wt[KC][BT + 4];   // Wt[kk][ii] = Wm[i0+ii][k0+kk]
    __shared__ float Et[KC][BT + 4];   // Et[kk][jj] = Es[k0+kk][j0+jj]
    int i0 = blockIdx.y * BT, j0 = blockIdx.x * BT;
    int tid = threadIdx.x;
    int tx = tid & 15, ty = tid >> 4;
    float prod[4][4];
    #pragma unroll
    for (int a = 0; a < 4; a++)
        #pragma unroll
        for (int b = 0; b < 4; b++) prod[a][b] = 1.f;

    for (int k0 = 0; k0 < TP; k0 += KC) {
        __syncthreads();
        #pragma unroll
        for (int e = tid; e < KC * BT; e += 256) {
            int v = e & 63, kk = e >> 6;
            int gi = i0 + v, gk = k0 + kk;
            float w = Es[(size_t)gi * TP + gk];
            if (lbl[gi] != lbl[gk] || gi == gk) w = 0.f;   // Wm: same-label, no diag
            Wt[kk][v] = w;
            Et[kk][v] = Es[(size_t)gk * TP + (j0 + v)];
        }
        __syncthreads();
        #pragma unroll
        for (int kk = 0; kk < KC; kk++) {
            float4 wv = *(const float4*)&Wt[kk][ty * 4];
            float4 ev = *(const float4*)&Et[kk][tx * 4];
            float w[4] = {wv.x, wv.y, wv.z, wv.w};
            float e[4] = {ev.x, ev.y, ev.z, ev.w};
            #pragma unroll
            for (int a = 0; a < 4; a++)
                #pragma unroll
                for (int b = 0; b < 4; b++)
                    prod[a][b] *= fmaf(-w[a], e[b], 1.f);
        }
    }
    // epilogue: A = -(attacks*blocked + sym)
    #pragma unroll
    for (int a = 0; a < 4; a++) {
        int i = i0 + ty * 4 + a;
        int li = lbl[i];
        float pi = p[i];
        #pragma unroll
        for (int b = 0; b < 4; b++) {
            int j = j0 + tx * 4 + b;
            float v = 0.f;
            if (i < TT && j < TT) {
                int lj = lbl[j];
                bool same = (li == lj);
                float es = Es[(size_t)i * TP + j];
                float att = same ? 0.f : es;
                float x = SCALE_C * (pi - p[j]);
                float sym = (!same && i < NTRAIN) ? sigm(x) * sigm(-x) : 0.f;
                v = -(att * prod[a][b] + sym);
            }
            Amat[(size_t)i * TP + j] = v;
        }
    }
}

// ---------------- c = base_logit - r, s0 = sigma(base_logit) ----------------
__global__ void k_cq(const float* __restrict__ Xtr, const float* __restrict__ Xdef,
                     const float* __restrict__ Xq, const float* __restrict__ bl,
                     const float* __restrict__ xsq,
                     float* __restrict__ c, float* __restrict__ s0) {
    int b = blockIdx.y;
    int t = blockIdx.x * 256 + threadIdx.x;
    if (t >= TP) return;
    float cv = 0.f, sv = 0.f;
    if (t < TT) {
        const float4* q4 = (const float4*)(Xq + (size_t)b * DDIM);
        const float* row = (t < NTRAIN) ? (Xtr + (size_t)t * DDIM)
                                        : (Xdef + (size_t)(t - NTRAIN) * DDIM);
        const float4* x4 = (const float4*)row;
        float dot = 0.f, qs = 0.f;
        #pragma unroll
        for (int d = 0; d < DDIM / 4; d++) {
            float4 q = q4[d], x = x4[d];
            dot = fmaf(q.x, x.x, fmaf(q.y, x.y, fmaf(q.z, x.z, fmaf(q.w, x.w, dot))));
            qs  = fmaf(q.x, q.x, fmaf(q.y, q.y, fmaf(q.z, q.z, fmaf(q.w, q.w, qs))));
        }
        float sq = qs + xsq[t] - 2.f * dot;
        float r = sigm(GAMMA_C * (sq - TAU_C));
        cv = bl[t] - r;
        sv = sigm(bl[t]);
    }
    c[(size_t)b * TP + t] = cv;
    s0[(size_t)b * TP + t] = sv;
}

// ---------------- one iteration: Snew = sigma(c + S@A) ----------------
#define GB 32
#define GJ 32
#define GK 32
__global__ __launch_bounds__(256) void k_iter(const float* __restrict__ S,
                                              const float* __restrict__ Amat,
                                              const float* __restrict__ c,
                                              float* __restrict__ Snew) {
    __shared__ float St[GK][GB + 4];   // St[kk][bb] = S[b0+bb][k0+kk]
    __shared__ float At[GK][GJ + 4];   // At[kk][jj] = A[k0+kk][j0+jj]
    int j0 = blockIdx.x * GJ, b0 = blockIdx.y * GB;
    int tid = threadIdx.x;
    int tx = tid & 15, ty = tid >> 4;
    float acc[2][2] = {{0.f, 0.f}, {0.f, 0.f}};
    for (int k0 = 0; k0 < TP; k0 += GK) {
        __syncthreads();
        #pragma unroll
        for (int e = tid; e < GK * GB; e += 256) {
            int v = e & 31, kk = e >> 5;
            St[kk][v] = S[(size_t)(b0 + v) * TP + k0 + kk];
            At[kk][v] = Amat[(size_t)(k0 + kk) * TP + j0 + v];
        }
        __syncthreads();
        #pragma unroll
        for (int kk = 0; kk < GK; kk++) {
            float2 sv = *(const float2*)&St[kk][ty * 2];
            float2 av = *(const float2*)&At[kk][tx * 2];
            acc[0][0] = fmaf(sv.x, av.x, acc[0][0]);
            acc[0][1] = fmaf(sv.x, av.y, acc[0][1]);
            acc[1][0] = fmaf(sv.y, av.x, acc[1][0]);
            acc[1][1] = fmaf(sv.y, av.y, acc[1][1]);
        }
    }
    #pragma unroll
    for (int a = 0; a < 2; a++) {
        int b = b0 + ty * 2 + a;
        #pragma unroll
        for (int bb = 0; bb < 2; bb++) {
            int j = j0 + tx * 2 + bb;
            float v = 0.f;
            if (j < TT) v = sigm(c[(size_t)b * TP + j] + acc[a][bb]);
            Snew[(size_t)b * TP + j] = v;   // pad cols stay 0 -> padded k-loop exact
        }
    }
}

// ---------------- extract last Y columns ----------------
__global__ void k_out(const float* __restrict__ S, float* __restrict__ out) {
    int idx = threadIdx.x + blockIdx.x * blockDim.x;
    if (idx < NB * NY) {
        int b = idx >> 1, y = idx & 1;
        out[idx] = S[(size_t)b * TP + NTRAIN + y];
    }
}

extern "C" void kernel_launch(void* const* d_in, const int* in_sizes, int n_in,
                              void* d_out, int out_size, void* d_ws, size_t ws_size,
                              hipStream_t stream) {
    const float* Xtr    = (const float*)d_in[0];
    const float* Xdef   = (const float*)d_in[1];
    const float* Xq     = (const float*)d_in[2];
    const float* worder = (const float*)d_in[3];
    const float* wbase  = (const float*)d_in[4];
    const int*   ytr    = (const int*)d_in[5];
    // d_in[6] = y_default_labels == arange(Y), not needed

    char* ws = (char*)d_ws;
    size_t off = 0;
    auto alloc = [&](size_t bytes) {
        void* r = ws + off;
        off += (bytes + 255) & ~(size_t)255;
        return r;
    };
    float* p    = (float*)alloc((size_t)TP * 4);
    float* bl   = (float*)alloc((size_t)TP * 4);
    float* xsq  = (float*)alloc((size_t)TP * 4);
    int*   lbl  = (int*)  alloc((size_t)TP * 4);
    float* Es   = (float*)alloc((size_t)TP * TP * 4);
    float* Amat = (float*)alloc((size_t)TP * TP * 4);
    float* c    = (float*)alloc((size_t)NB * TP * 4);
    float* s0   = (float*)alloc((size_t)NB * TP * 4);
    float* s1   = (float*)alloc((size_t)NB * TP * 4);

    k_prep<<<TP, 128, 0, stream>>>(Xtr, Xdef, worder, wbase, ytr, p, bl, xsq, lbl);
    k_es<<<dim3((TP + 255) / 256, TP), 256, 0, stream>>>(p, Es);
    k_ablk<<<dim3(TP / BT, TP / BT), 256, 0, stream>>>(Es, p, lbl, Amat);
    k_cq<<<dim3((TP + 255) / 256, NB), 256, 0, stream>>>(Xtr, Xdef, Xq, bl, xsq, c, s0);

    float* cur = s0;
    float* nxt = s1;
    for (int it = 0; it < NITER; it++) {
        k_iter<<<dim3(TP / GJ, NB / GB), 256, 0, stream>>>(cur, Amat, c, nxt);
        float* t = cur; cur = nxt; nxt = t;
    }
    k_out<<<1, 512, 0, stream>>>(cur, (float*)d_out);
}

// Round 2
// 1160.653 us; speedup vs baseline: 1.1034x; 1.1034x over previous
//
#include <hip/hip_runtime.h>

#define NTRAIN 1024
#define NY 2
#define DDIM 128
#define NB 256
#define NITER 16
#define TT 1026          // NTRAIN + NY
#define TP 1088          // padded to 64-multiple
#define SCALE_C 0.25f
#define GAMMA_C 0.05f
#define TAU_C 256.0f     // 2*D

__device__ __forceinline__ float sigm(float x) {
    return 1.0f / (1.0f + __expf(-x));
}

// ---------------- prep: p, base_logit, xsq, labels ----------------
__global__ void k_prep(const float* __restrict__ Xtr, const float* __restrict__ Xdef,
                       const float* __restrict__ worder, const float* __restrict__ wbase,
                       const int* __restrict__ ytr,
                       float* __restrict__ p, float* __restrict__ bl,
                       float* __restrict__ xsq, int* __restrict__ lbl) {
    int t = blockIdx.x;        // 0..TP-1
    int tx = threadIdx.x;      // 128 threads
    __shared__ float sp[128], sb[128], ss[128];
    float po = 0.f, bo = 0.f, sq = 0.f;
    if (t < TT) {
        const float* row = (t < NTRAIN) ? (Xtr + (size_t)t * DDIM)
                                        : (Xdef + (size_t)(t - NTRAIN) * DDIM);
        float x = row[tx];
        po = x * worder[tx];
        bo = x * wbase[tx];
        sq = x * x;
    }
    sp[tx] = po; sb[tx] = bo; ss[tx] = sq;
    __syncthreads();
    for (int off = 64; off > 0; off >>= 1) {
        if (tx < off) { sp[tx] += sp[tx+off]; sb[tx] += sb[tx+off]; ss[tx] += ss[tx+off]; }
        __syncthreads();
    }
    if (tx == 0) {
        p[t] = sp[0]; bl[t] = sb[0]; xsq[t] = ss[0];
        lbl[t] = (t < NTRAIN) ? ytr[t] : ((t < TT) ? (t - NTRAIN) : -1);
    }
}

// ---------------- Es[i,j] (default rows + pad zeroed) ----------------
__global__ void k_es(const float* __restrict__ p, float* __restrict__ Es) {
    int j = blockIdx.x * blockDim.x + threadIdx.x;
    int i = blockIdx.y;
    if (j >= TP) return;
    float v = 0.f;
    if (i < NTRAIN && j < TT) {   // is_default rows (i>=NTRAIN) and pads -> 0
        float x = SCALE_C * (p[i] - p[j]);
        float a = sigm(x);
        float b = sigm(-x);
        v = a * (1.f - b);
    }
    Es[(size_t)i * TP + j] = v;
}

// ---------------- partial blocked product (split-K over blockIdx.z) ----------------
#define BT 64
#define KC 16
__global__ __launch_bounds__(256) void k_pblk(const float* __restrict__ Es,
                                              const int* __restrict__ lbl,
                                              float* __restrict__ P, int kspan) {
    __shared__ float Wt[KC][BT + 4];   // Wt[kk][ii] = Wm[i0+ii][k0+kk]
    __shared__ float Et[KC][BT + 4];   // Et[kk][jj] = Es[k0+kk][j0+jj]
    int i0 = blockIdx.y * BT, j0 = blockIdx.x * BT;
    int ks = blockIdx.z * kspan, ke = ks + kspan;
    int tid = threadIdx.x;
    int tx = tid & 15, ty = tid >> 4;
    float prod[4][4];
    #pragma unroll
    for (int a = 0; a < 4; a++)
        #pragma unroll
        for (int b = 0; b < 4; b++) prod[a][b] = 1.f;

    for (int k0 = ks; k0 < ke; k0 += KC) {
        __syncthreads();
        #pragma unroll
        for (int e = tid; e < KC * BT; e += 256) {   // Wt: kk fast -> coalesced-ish
            int kk = e & 15, ii = e >> 4;
            int gi = i0 + ii, gk = k0 + kk;
            float w = Es[(size_t)gi * TP + gk];
            if (lbl[gi] != lbl[gk] || gi == gk) w = 0.f;   // Wm: same-label, no diag
            Wt[kk][ii] = w;
        }
        #pragma unroll
        for (int e = tid; e < KC * BT; e += 256) {   // Et: jj fast -> coalesced
            int jj = e & 63, kk = e >> 6;
            Et[kk][jj] = Es[(size_t)(k0 + kk) * TP + j0 + jj];
        }
        __syncthreads();
        #pragma unroll
        for (int kk = 0; kk < KC; kk++) {
            float4 wv = *(const float4*)&Wt[kk][ty * 4];
            float4 ev = *(const float4*)&Et[kk][tx * 4];
            float w[4] = {wv.x, wv.y, wv.z, wv.w};
            float e[4] = {ev.x, ev.y, ev.z, ev.w};
            #pragma unroll
            for (int a = 0; a < 4; a++)
                #pragma unroll
                for (int b = 0; b < 4; b++)
                    prod[a][b] *= fmaf(-w[a], e[b], 1.f);
        }
    }
    float* Pz = P + (size_t)blockIdx.z * TP * TP;
    #pragma unroll
    for (int a = 0; a < 4; a++) {
        int i = i0 + ty * 4 + a;
        *(float4*)&Pz[(size_t)i * TP + j0 + tx * 4] =
            make_float4(prod[a][0], prod[a][1], prod[a][2], prod[a][3]);
    }
}

// ---------------- combine partials + assemble A (in place over P[0]) ----------------
__global__ void k_afin(float* __restrict__ P, int splits,
                       const float* __restrict__ Es, const float* __restrict__ p,
                       const int* __restrict__ lbl, float* __restrict__ A) {
    size_t idx = (size_t)blockIdx.x * 256 + threadIdx.x;
    if (idx >= (size_t)TP * TP) return;
    int i = (int)(idx / TP), j = (int)(idx % TP);
    float prod = P[idx];
    for (int r = 1; r < splits; r++) prod *= P[(size_t)r * TP * TP + idx];
    float v = 0.f;
    if (i < TT && j < TT) {
        int li = lbl[i], lj = lbl[j];
        bool same = (li == lj);
        float es = Es[idx];
        float att = same ? 0.f : es;
        float x = SCALE_C * (p[i] - p[j]);
        float sym = (!same && i < NTRAIN) ? sigm(x) * sigm(-x) : 0.f;
        v = -(att * prod + sym);
    }
    A[idx] = v;
}

// ---------------- c = base_logit - r, s0 = sigma(base_logit) ----------------
__global__ void k_cq(const float* __restrict__ Xtr, const float* __restrict__ Xdef,
                     const float* __restrict__ Xq, const float* __restrict__ bl,
                     const float* __restrict__ xsq,
                     float* __restrict__ c, float* __restrict__ s0) {
    int b = blockIdx.y;
    int t = blockIdx.x * 256 + threadIdx.x;
    if (t >= TP) return;
    float cv = 0.f, sv = 0.f;
    if (t < TT) {
        const float4* q4 = (const float4*)(Xq + (size_t)b * DDIM);
        const float* row = (t < NTRAIN) ? (Xtr + (size_t)t * DDIM)
                                        : (Xdef + (size_t)(t - NTRAIN) * DDIM);
        const float4* x4 = (const float4*)row;
        float dot = 0.f, qs = 0.f;
        #pragma unroll
        for (int d = 0; d < DDIM / 4; d++) {
            float4 q = q4[d], x = x4[d];
            dot = fmaf(q.x, x.x, fmaf(q.y, x.y, fmaf(q.z, x.z, fmaf(q.w, x.w, dot))));
            qs  = fmaf(q.x, q.x, fmaf(q.y, q.y, fmaf(q.z, q.z, fmaf(q.w, q.w, qs))));
        }
        float sq = qs + xsq[t] - 2.f * dot;
        float r = sigm(GAMMA_C * (sq - TAU_C));
        cv = bl[t] - r;
        sv = sigm(bl[t]);
    }
    c[(size_t)b * TP + t] = cv;
    s0[(size_t)b * TP + t] = sv;
}

// ---------------- one iteration: Snew = sigma(c + S@A) ----------------
#define GB 32
#define GJ 32
#define GKC 64
__global__ __launch_bounds__(256) void k_iter(const float* __restrict__ S,
                                              const float* __restrict__ Amat,
                                              const float* __restrict__ c,
                                              float* __restrict__ Snew) {
    __shared__ float St[GKC][GB + 2];   // St[kk][bb] = S[b0+bb][k0+kk]
    __shared__ float At[GKC][GJ + 2];   // At[kk][jj] = A[k0+kk][j0+jj]
    int j0 = blockIdx.x * GJ, b0 = blockIdx.y * GB;
    int tid = threadIdx.x;
    int tx = tid & 15, ty = tid >> 4;
    float acc[2][2] = {{0.f, 0.f}, {0.f, 0.f}};
    for (int k0 = 0; k0 < TP; k0 += GKC) {
        __syncthreads();
        #pragma unroll
        for (int e = tid; e < GKC * GB; e += 256) {   // kk fast -> coalesced
            int kk = e & 63, bb = e >> 6;
            St[kk][bb] = S[(size_t)(b0 + bb) * TP + k0 + kk];
        }
        #pragma unroll
        for (int e = tid; e < GKC * GJ; e += 256) {   // jj fast -> coalesced
            int jj = e & 31, kk = e >> 5;
            At[kk][jj] = Amat[(size_t)(k0 + kk) * TP + j0 + jj];
        }
        __syncthreads();
        #pragma unroll 16
        for (int kk = 0; kk < GKC; kk++) {
            float2 sv = *(const float2*)&St[kk][ty * 2];
            float2 av = *(const float2*)&At[kk][tx * 2];
            acc[0][0] = fmaf(sv.x, av.x, acc[0][0]);
            acc[0][1] = fmaf(sv.x, av.y, acc[0][1]);
            acc[1][0] = fmaf(sv.y, av.x, acc[1][0]);
            acc[1][1] = fmaf(sv.y, av.y, acc[1][1]);
        }
    }
    #pragma unroll
    for (int a = 0; a < 2; a++) {
        int b = b0 + ty * 2 + a;
        #pragma unroll
        for (int bb = 0; bb < 2; bb++) {
            int j = j0 + tx * 2 + bb;
            float v = 0.f;
            if (j < TT) v = sigm(c[(size_t)b * TP + j] + acc[a][bb]);
            Snew[(size_t)b * TP + j] = v;   // pad cols stay 0 -> padded k-loop exact
        }
    }
}

// ---------------- extract last Y columns ----------------
__global__ void k_out(const float* __restrict__ S, float* __restrict__ out) {
    int idx = threadIdx.x + blockIdx.x * blockDim.x;
    if (idx < NB * NY) {
        int b = idx >> 1, y = idx & 1;
        out[idx] = S[(size_t)b * TP + NTRAIN + y];
    }
}

extern "C" void kernel_launch(void* const* d_in, const int* in_sizes, int n_in,
                              void* d_out, int out_size, void* d_ws, size_t ws_size,
                              hipStream_t stream) {
    const float* Xtr    = (const float*)d_in[0];
    const float* Xdef   = (const float*)d_in[1];
    const float* Xq     = (const float*)d_in[2];
    const float* worder = (const float*)d_in[3];
    const float* wbase  = (const float*)d_in[4];
    const int*   ytr    = (const int*)d_in[5];

    const size_t MAT = (size_t)TP * TP * 4;        // 4.73 MB
    const size_t VEC = (size_t)NB * TP * 4;        // 1.11 MB
    // pick split count that fits the workspace
    auto need = [&](int s) {
        return (size_t)4 * 4608 + MAT /*Es*/ + (size_t)s * MAT /*P*/ + 3 * VEC + 4096;
    };
    int splits = 4;
    if (ws_size < need(4)) splits = 2;
    if (ws_size < need(2)) splits = 1;

    char* ws = (char*)d_ws;
    size_t off = 0;
    auto alloc = [&](size_t bytes) {
        void* r = ws + off;
        off += (bytes + 255) & ~(size_t)255;
        return r;
    };
    float* p    = (float*)alloc((size_t)TP * 4);
    float* bl   = (float*)alloc((size_t)TP * 4);
    float* xsq  = (float*)alloc((size_t)TP * 4);
    int*   lbl  = (int*)  alloc((size_t)TP * 4);
    float* Es   = (float*)alloc(MAT);
    float* P    = (float*)alloc((size_t)splits * MAT);   // P[0] becomes A in place
    float* c    = (float*)alloc(VEC);
    float* s0   = (float*)alloc(VEC);
    float* s1   = (float*)alloc(VEC);
    float* Amat = P;   // k_afin writes A over P[0] (elementwise-safe)

    int kspan = TP / splits;

    k_prep<<<TP, 128, 0, stream>>>(Xtr, Xdef, worder, wbase, ytr, p, bl, xsq, lbl);
    k_es<<<dim3((TP + 255) / 256, TP), 256, 0, stream>>>(p, Es);
    k_pblk<<<dim3(TP / BT, TP / BT, splits), 256, 0, stream>>>(Es, lbl, P, kspan);
    k_afin<<<(int)(((size_t)TP * TP + 255) / 256), 256, 0, stream>>>(P, splits, Es, p, lbl, Amat);
    k_cq<<<dim3((TP + 255) / 256, NB), 256, 0, stream>>>(Xtr, Xdef, Xq, bl, xsq, c, s0);

    float* cur = s0;
    float* nxt = s1;
    for (int it = 0; it < NITER; it++) {
        k_iter<<<dim3(TP / GJ, NB / GB), 256, 0, stream>>>(cur, Amat, c, nxt);
        float* t = cur; cur = nxt; nxt = t;
    }
    k_out<<<1, 512, 0, stream>>>(cur, (float*)d_out);
}

// Round 3
// 599.466 us; speedup vs baseline: 2.1363x; 1.9361x over previous
//
#include <hip/hip_runtime.h>

#define NTRAIN 1024
#define NY 2
#define DDIM 128
#define NB 256
#define NITER 16
#define TT 1026          // NTRAIN + NY
#define TP 1088          // padded to 64-multiple (17*64)
#define SCALE_C 0.25f
#define GAMMA_C 0.05f
#define TAU_C 256.0f     // 2*D
#define KSPLIT 16        // split-K factor for the iteration GEMM
#define KSPAN (TP / KSPLIT)   // 68

__device__ __forceinline__ float sigm(float x) {
    return 1.0f / (1.0f + __expf(-x));
}

// ---------------- prep: p, base_logit, xsq, labels ----------------
__global__ void k_prep(const float* __restrict__ Xtr, const float* __restrict__ Xdef,
                       const float* __restrict__ worder, const float* __restrict__ wbase,
                       const int* __restrict__ ytr,
                       float* __restrict__ p, float* __restrict__ bl,
                       float* __restrict__ xsq, int* __restrict__ lbl) {
    int t = blockIdx.x;        // 0..TP-1
    int tx = threadIdx.x;      // 128 threads
    __shared__ float sp[128], sb[128], ss[128];
    float po = 0.f, bo = 0.f, sq = 0.f;
    if (t < TT) {
        const float* row = (t < NTRAIN) ? (Xtr + (size_t)t * DDIM)
                                        : (Xdef + (size_t)(t - NTRAIN) * DDIM);
        float x = row[tx];
        po = x * worder[tx];
        bo = x * wbase[tx];
        sq = x * x;
    }
    sp[tx] = po; sb[tx] = bo; ss[tx] = sq;
    __syncthreads();
    for (int off = 64; off > 0; off >>= 1) {
        if (tx < off) { sp[tx] += sp[tx+off]; sb[tx] += sb[tx+off]; ss[tx] += ss[tx+off]; }
        __syncthreads();
    }
    if (tx == 0) {
        p[t] = sp[0]; bl[t] = sb[0]; xsq[t] = ss[0];
        lbl[t] = (t < NTRAIN) ? ytr[t] : ((t < TT) ? (t - NTRAIN) : -1);
    }
}

// ---------------- Es[i,j] (default rows + pad zeroed) ----------------
__global__ void k_es(const float* __restrict__ p, float* __restrict__ Es) {
    int j = blockIdx.x * blockDim.x + threadIdx.x;
    int i = blockIdx.y;
    if (j >= TP) return;
    float v = 0.f;
    if (i < NTRAIN && j < TT) {   // is_default rows (i>=NTRAIN) and pads -> 0
        float x = SCALE_C * (p[i] - p[j]);
        float a = sigm(x);
        float b = sigm(-x);
        v = a * (1.f - b);
    }
    Es[(size_t)i * TP + j] = v;
}

// ---------------- partial blocked product (split-K over blockIdx.z) ----------------
#define BT 64
#define KC 32
__global__ __launch_bounds__(256) void k_pblk(const float* __restrict__ Es,
                                              const int* __restrict__ lbl,
                                              float* __restrict__ P, int kspan) {
    __shared__ float Wt[KC][BT + 4];   // Wt[kk][ii] = Wm[i0+ii][k0+kk]
    __shared__ float Et[KC][BT + 4];   // Et[kk][jj] = Es[k0+kk][j0+jj]
    int i0 = blockIdx.y * BT, j0 = blockIdx.x * BT;
    int ks = blockIdx.z * kspan, ke = ks + kspan;
    int tid = threadIdx.x;
    int tx = tid & 15, ty = tid >> 4;
    float prod[4][4];
    #pragma unroll
    for (int a = 0; a < 4; a++)
        #pragma unroll
        for (int b = 0; b < 4; b++) prod[a][b] = 1.f;

    for (int k0 = ks; k0 < ke; k0 += KC) {
        __syncthreads();
        #pragma unroll
        for (int e = tid; e < KC * BT; e += 256) {   // Wt: kk fast -> coalesced reads
            int kk = e & (KC - 1), ii = e >> 5;
            int gi = i0 + ii, gk = k0 + kk;
            float w = Es[(size_t)gi * TP + gk];
            if (lbl[gi] != lbl[gk] || gi == gk) w = 0.f;   // Wm: same-label, no diag
            Wt[kk][ii] = w;
        }
        #pragma unroll
        for (int e = tid; e < KC * BT; e += 256) {   // Et: jj fast -> coalesced
            int jj = e & 63, kk = e >> 6;
            Et[kk][jj] = Es[(size_t)(k0 + kk) * TP + j0 + jj];
        }
        __syncthreads();
        #pragma unroll
        for (int kk = 0; kk < KC; kk++) {
            float4 wv = *(const float4*)&Wt[kk][ty * 4];
            float4 ev = *(const float4*)&Et[kk][tx * 4];
            float w[4] = {wv.x, wv.y, wv.z, wv.w};
            float e[4] = {ev.x, ev.y, ev.z, ev.w};
            #pragma unroll
            for (int a = 0; a < 4; a++)
                #pragma unroll
                for (int b = 0; b < 4; b++)
                    prod[a][b] *= fmaf(-w[a], e[b], 1.f);
        }
    }
    float* Pz = P + (size_t)blockIdx.z * TP * TP;
    #pragma unroll
    for (int a = 0; a < 4; a++) {
        int i = i0 + ty * 4 + a;
        *(float4*)&Pz[(size_t)i * TP + j0 + tx * 4] =
            make_float4(prod[a][0], prod[a][1], prod[a][2], prod[a][3]);
    }
}

// ---------------- combine partials + assemble A ----------------
__global__ void k_afin(const float* __restrict__ P, int splits,
                       const float* __restrict__ Es, const float* __restrict__ p,
                       const int* __restrict__ lbl, float* __restrict__ A) {
    size_t idx = (size_t)blockIdx.x * 256 + threadIdx.x;
    if (idx >= (size_t)TP * TP) return;
    int i = (int)(idx / TP), j = (int)(idx % TP);
    float prod = P[idx];
    for (int r = 1; r < splits; r++) prod *= P[(size_t)r * TP * TP + idx];
    float v = 0.f;
    if (i < TT && j < TT) {
        int li = lbl[i], lj = lbl[j];
        bool same = (li == lj);
        float es = Es[idx];
        float att = same ? 0.f : es;
        float x = SCALE_C * (p[i] - p[j]);
        float sym = (!same && i < NTRAIN) ? sigm(x) * sigm(-x) : 0.f;
        v = -(att * prod + sym);
    }
    A[idx] = v;
}

// ---------------- c = base_logit - r, s0 = sigma(base_logit) ----------------
__global__ void k_cq(const float* __restrict__ Xtr, const float* __restrict__ Xdef,
                     const float* __restrict__ Xq, const float* __restrict__ bl,
                     const float* __restrict__ xsq,
                     float* __restrict__ c, float* __restrict__ s0) {
    int b = blockIdx.y;
    int t = blockIdx.x * 256 + threadIdx.x;
    if (t >= TP) return;
    float cv = 0.f, sv = 0.f;
    if (t < TT) {
        const float4* q4 = (const float4*)(Xq + (size_t)b * DDIM);
        const float* row = (t < NTRAIN) ? (Xtr + (size_t)t * DDIM)
                                        : (Xdef + (size_t)(t - NTRAIN) * DDIM);
        const float4* x4 = (const float4*)row;
        float dot = 0.f, qs = 0.f;
        #pragma unroll
        for (int d = 0; d < DDIM / 4; d++) {
            float4 q = q4[d], x = x4[d];
            dot = fmaf(q.x, x.x, fmaf(q.y, x.y, fmaf(q.z, x.z, fmaf(q.w, x.w, dot))));
            qs  = fmaf(q.x, q.x, fmaf(q.y, q.y, fmaf(q.z, q.z, fmaf(q.w, q.w, qs))));
        }
        float sq = qs + xsq[t] - 2.f * dot;
        float r = sigm(GAMMA_C * (sq - TAU_C));
        cv = bl[t] - r;
        sv = sigm(bl[t]);
    }
    c[(size_t)b * TP + t] = cv;
    s0[(size_t)b * TP + t] = sv;
}

// ---------------- iteration partial: part[z] = S[:, ks:ke] @ A[ks:ke, :] ----------------
// grid: (TP/64, NB/64, KSPLIT); 256 threads; 64x64 tile, 4x4 micro-tile.
// Whole k-span (68) staged once -> one barrier per launch, then pure LDS compute.
__global__ __launch_bounds__(256) void k_ipart(const float* __restrict__ S,
                                               const float* __restrict__ Amat,
                                               float* __restrict__ part) {
    __shared__ float St[KSPAN][68];   // St[kk][bb] = S[b0+bb][k0+kk]  (68 stride: 16B-aligned rows)
    __shared__ float At[KSPAN][68];   // At[kk][jj] = A[k0+kk][j0+jj]
    int j0 = blockIdx.x * 64, b0 = blockIdx.y * 64;
    int k0 = blockIdx.z * KSPAN;
    int tid = threadIdx.x;
    int tx = tid & 15, ty = tid >> 4;

    // stage S slab: kk fast -> coalesced global reads (68-float rows)
    for (int e = tid; e < 64 * KSPAN; e += 256) {
        int kk = e % KSPAN, bb = e / KSPAN;
        St[kk][bb] = S[(size_t)(b0 + bb) * TP + k0 + kk];
    }
    // stage A slab: jj fast -> coalesced
    for (int e = tid; e < 64 * KSPAN; e += 256) {
        int jj = e & 63, kk = e >> 6;
        At[kk][jj] = Amat[(size_t)(k0 + kk) * TP + j0 + jj];
    }
    __syncthreads();

    float acc[4][4];
    #pragma unroll
    for (int a = 0; a < 4; a++)
        #pragma unroll
        for (int b = 0; b < 4; b++) acc[a][b] = 0.f;

    #pragma unroll 4
    for (int kk = 0; kk < KSPAN; kk++) {
        float4 sv = *(const float4*)&St[kk][ty * 4];   // broadcast within 16-lane groups
        float4 av = *(const float4*)&At[kk][tx * 4];
        float s[4] = {sv.x, sv.y, sv.z, sv.w};
        float a4[4] = {av.x, av.y, av.z, av.w};
        #pragma unroll
        for (int a = 0; a < 4; a++)
            #pragma unroll
            for (int b = 0; b < 4; b++)
                acc[a][b] = fmaf(s[a], a4[b], acc[a][b]);
    }

    float* Pz = part + (size_t)blockIdx.z * NB * TP;
    #pragma unroll
    for (int a = 0; a < 4; a++) {
        int b = b0 + ty * 4 + a;
        *(float4*)&Pz[(size_t)b * TP + j0 + tx * 4] =
            make_float4(acc[a][0], acc[a][1], acc[a][2], acc[a][3]);
    }
}

// ---------------- combine split-K partials + sigmoid ----------------
__global__ void k_comb(const float* __restrict__ part, const float* __restrict__ c,
                       float* __restrict__ Snew) {
    size_t idx = (size_t)blockIdx.x * 256 + threadIdx.x;
    if (idx >= (size_t)NB * TP) return;
    int j = (int)(idx % TP);
    float sum = 0.f;
    #pragma unroll
    for (int z = 0; z < KSPLIT; z++) sum += part[(size_t)z * NB * TP + idx];
    float v = 0.f;
    if (j < TT) v = sigm(c[idx] + sum);
    Snew[idx] = v;   // pad cols stay 0 -> padded k-loop exact
}

// ---------------- extract last Y columns ----------------
__global__ void k_out(const float* __restrict__ S, float* __restrict__ out) {
    int idx = threadIdx.x + blockIdx.x * blockDim.x;
    if (idx < NB * NY) {
        int b = idx >> 1, y = idx & 1;
        out[idx] = S[(size_t)b * TP + NTRAIN + y];
    }
}

extern "C" void kernel_launch(void* const* d_in, const int* in_sizes, int n_in,
                              void* d_out, int out_size, void* d_ws, size_t ws_size,
                              hipStream_t stream) {
    const float* Xtr    = (const float*)d_in[0];
    const float* Xdef   = (const float*)d_in[1];
    const float* Xq     = (const float*)d_in[2];
    const float* worder = (const float*)d_in[3];
    const float* wbase  = (const float*)d_in[4];
    const int*   ytr    = (const int*)d_in[5];

    const size_t MAT = (size_t)TP * TP * 4;        // 4.73 MB
    const size_t VEC = (size_t)NB * TP * 4;        // 1.11 MB
    const size_t SMALL = 4 * 4608;
    // P region is reused as split-K partial buffers (16*VEC <= 4*MAT)
    auto need = [&](int s) {
        size_t preg = (size_t)s * MAT;
        if (preg < (size_t)KSPLIT * VEC) preg = (size_t)KSPLIT * VEC;
        return SMALL + MAT /*Es*/ + MAT /*A*/ + preg + 3 * VEC + 8192;
    };
    int splits = 8;
    if (ws_size < need(8)) splits = 4;
    if (ws_size < need(4)) splits = 2;

    char* ws = (char*)d_ws;
    size_t off = 0;
    auto alloc = [&](size_t bytes) {
        void* r = ws + off;
        off += (bytes + 255) & ~(size_t)255;
        return r;
    };
    float* p    = (float*)alloc((size_t)TP * 4);
    float* bl   = (float*)alloc((size_t)TP * 4);
    float* xsq  = (float*)alloc((size_t)TP * 4);
    int*   lbl  = (int*)  alloc((size_t)TP * 4);
    float* Es   = (float*)alloc(MAT);
    float* Amat = (float*)alloc(MAT);
    size_t preg = (size_t)splits * MAT;
    if (preg < (size_t)KSPLIT * VEC) preg = (size_t)KSPLIT * VEC;
    float* P    = (float*)alloc(preg);     // k_pblk partials, then k_ipart partials
    float* c    = (float*)alloc(VEC);
    float* s0   = (float*)alloc(VEC);
    float* s1   = (float*)alloc(VEC);

    int kspan = TP / splits;

    k_prep<<<TP, 128, 0, stream>>>(Xtr, Xdef, worder, wbase, ytr, p, bl, xsq, lbl);
    k_es<<<dim3((TP + 255) / 256, TP), 256, 0, stream>>>(p, Es);
    k_pblk<<<dim3(TP / BT, TP / BT, splits), 256, 0, stream>>>(Es, lbl, P, kspan);
    k_afin<<<(int)(((size_t)TP * TP + 255) / 256), 256, 0, stream>>>(P, splits, Es, p, lbl, Amat);
    k_cq<<<dim3((TP + 255) / 256, NB), 256, 0, stream>>>(Xtr, Xdef, Xq, bl, xsq, c, s0);

    float* cur = s0;
    float* nxt = s1;
    const int nvec = (int)(((size_t)NB * TP + 255) / 256);
    for (int it = 0; it < NITER; it++) {
        k_ipart<<<dim3(TP / 64, NB / 64, KSPLIT), 256, 0, stream>>>(cur, Amat, P);
        k_comb<<<nvec, 256, 0, stream>>>(P, c, nxt);
        float* t = cur; cur = nxt; nxt = t;
    }
    k_out<<<1, 512, 0, stream>>>(cur, (float*)d_out);
}